// Round 2
// baseline (104.131 us; speedup 1.0000x reference)
//
#include <hip/hip_runtime.h>
#include <math.h>

#define NIMG 24        // B*C = 8*3
#define H    256
#define W    256
#define NPIX (H * W)
#define NROWS (NIMG * H)
#define NBLK (NIMG * W)
#define BIGF 1.0e6f

// ---------------------------------------------------------------------------
// Wave-level inclusive max scans (64 lanes)
// ---------------------------------------------------------------------------
__device__ __forceinline__ float wscan_fwd_max(float v, int lane) {
#pragma unroll
    for (int off = 1; off < 64; off <<= 1) {
        float u = __shfl_up(v, off, 64);
        if (lane >= off) v = fmaxf(v, u);
    }
    return v;
}
__device__ __forceinline__ float wscan_rev_max(float v, int lane) {
#pragma unroll
    for (int off = 1; off < 64; off <<= 1) {
        float u = __shfl_down(v, off, 64);
        if (lane + off < 64) v = fmaxf(v, u);
    }
    return v;
}

// ---------------------------------------------------------------------------
// Pass 1: one WAVE per row (lane owns 4 columns). Computes 1-D EDT for both
// polarities via per-lane prefix + wave shfl-scan, stores TRANSPOSED
// h[img][j][row] = g*g + row*row  (the +row^2 feeds pass 2's exact
// (i-k)^2 = k^2 - 2ik + i^2 decomposition; all values are exact fp32 ints).
// ---------------------------------------------------------------------------
__global__ void edt_rows_kernel(const int* __restrict__ tgt,
                                float* __restrict__ hpT,
                                float* __restrict__ hnT,
                                int* __restrict__ flags) {
    const int tid  = blockIdx.x * 256 + threadIdx.x;
    const int gw   = tid >> 6;          // global wave id == row id (0..6143)
    const int lane = tid & 63;
    const int img  = gw >> 8;
    const int row  = gw & 255;

    const int4 tv = ((const int4*)(tgt + (img << 16) + (row << 8)))[lane];
    const float c0 = (float)(lane << 2);
    const float c1 = c0 + 1.0f, c2 = c0 + 2.0f, c3 = c0 + 3.0f;
    const float rsq = (float)(row * row);

    float* outp = hpT + (img << 16) + row;
    float* outn = hnT + (img << 16) + row;

    auto polarity = [&](bool z0, bool z1, bool z2, bool z3, float* __restrict__ out) {
        // forward: last = inclusive cummax of (z ? col : -BIG)
        float a0 = z0 ? c0 : -BIGF;
        float a1 = fmaxf(z1 ? c1 : -BIGF, a0);
        float a2 = fmaxf(z2 ? c2 : -BIGF, a1);
        float a3 = fmaxf(z3 ? c3 : -BIGF, a2);
        float s  = wscan_fwd_max(a3, lane);
        float ex = __shfl_up(s, 1, 64);
        if (lane == 0) ex = -BIGF;
        // backward: inclusive reverse cummax of (z ? -col : -BIG); nxt = -that
        float b3 = z3 ? -c3 : -BIGF;
        float b2 = fmaxf(z2 ? -c2 : -BIGF, b3);
        float b1 = fmaxf(z1 ? -c1 : -BIGF, b2);
        float b0 = fmaxf(z0 ? -c0 : -BIGF, b1);
        float sr  = wscan_rev_max(b0, lane);
        float exr = __shfl_down(sr, 1, 64);
        if (lane == 63) exr = -BIGF;

        float l0 = fmaxf(ex, a0), l1 = fmaxf(ex, a1);
        float l2 = fmaxf(ex, a2), l3 = fmaxf(ex, a3);
        float n0 = fmaxf(exr, b0), n1 = fmaxf(exr, b1);
        float n2 = fmaxf(exr, b2), n3 = fmaxf(exr, b3);

        float g0 = fminf(fminf(c0 - l0, -n0 - c0), BIGF);
        float g1 = fminf(fminf(c1 - l1, -n1 - c1), BIGF);
        float g2 = fminf(fminf(c2 - l2, -n2 - c2), BIGF);
        float g3 = fminf(fminf(c3 - l3, -n3 - c3), BIGF);

        out[(size_t)((lane << 2) + 0) << 8] = g0 * g0 + rsq;
        out[(size_t)((lane << 2) + 1) << 8] = g1 * g1 + rsq;
        out[(size_t)((lane << 2) + 2) << 8] = g2 * g2 + rsq;
        out[(size_t)((lane << 2) + 3) << 8] = g3 * g3 + rsq;
    };

    // pos transform: zeros where t == 0 ; neg transform: zeros where t != 0
    polarity(tv.x == 0, tv.y == 0, tv.z == 0, tv.w == 0, outp);
    polarity(tv.x != 0, tv.y != 0, tv.z != 0, tv.w != 0, outn);

    const int nz = tv.x | tv.y | tv.z | tv.w;
    if (__any(nz != 0)) {
        if (lane == 0) atomicOr(&flags[img], 1);
    }
}

// ---------------------------------------------------------------------------
// Pass 2: one block per (img, column j); thread i computes ONLY the polarity
// it needs (the other transform is exactly 0 at that pixel):
//   D2[i] = min_k h[k] + (i^2 - 2 i k)   with h[k] = g2[k] + k^2
// All terms are exact fp32 integers < 2^24 -> bitwise equal to reference.
// ---------------------------------------------------------------------------
__global__ void edt_cols_kernel(const float* __restrict__ hpT,
                                const float* __restrict__ hnT,
                                const float* __restrict__ pred,
                                const int* __restrict__ tgt,
                                const int* __restrict__ flags,
                                double* __restrict__ partials) {
    const int blk = blockIdx.x;        // img*W + j
    const int img = blk >> 8;
    const int j   = blk & 255;
    const int i   = threadIdx.x;

    __shared__ float sh[2][H];
    const int cbase = (img << 16) + (j << 8);
    sh[0][i] = hpT[cbase + i];
    sh[1][i] = hnT[cbase + i];
    __syncthreads();

    const int m = tgt[(img << 16) + (i << 8) + j];
    const float* h = sh[m ? 0 : 1];    // foreground -> pos transform

    const float fi  = (float)i;
    const float i2  = fi * fi;
    const float n2i = -2.0f * fi;      // exact
    const float t2  = 2.0f * n2i;      // -4i exact
    const float t3  = 3.0f * n2i;      // -6i exact

    float dm0 = 3.0e38f, dm1 = 3.0e38f, dm2 = 3.0e38f, dm3 = 3.0e38f;
    float fkg = 0.0f;
#pragma unroll 8
    for (int k = 0; k < H; k += 4) {
        const float4 hv = *(const float4*)(h + k);
        const float qg = fmaf(n2i, fkg, i2);   // i^2 - 2ik, exact int
        dm0 = fminf(dm0, hv.x + qg);
        dm1 = fminf(dm1, hv.y + (qg + n2i));
        dm2 = fminf(dm2, hv.z + (qg + t2));
        dm3 = fminf(dm3, hv.w + (qg + t3));
        fkg += 4.0f;
    }
    float dm = fminf(fminf(dm0, dm1), fminf(dm2, dm3));

    float d = sqrtf(dm);
    d = m ? d : -d;                    // d = pos - neg, one side is exactly 0
    if (flags[img] == 0) d = 0.0f;

    const float p = pred[(img << 16) + (i << 8) + j];
    const float sig = 1.0f / (1.0f + expf(-p));
    const double term = (double)sig * (double)d;

    __shared__ double sred[H];
    sred[i] = term;
    __syncthreads();
#pragma unroll
    for (int off = H / 2; off > 0; off >>= 1) {
        if (i < off) sred[i] += sred[i + off];
        __syncthreads();
    }
    if (i == 0) partials[blk] = sred[0];
}

// ---------------------------------------------------------------------------
// Finalize: deterministic sum of 6144 partials -> mean -> fp32
// ---------------------------------------------------------------------------
__global__ void finalize_kernel(const double* __restrict__ partials,
                                float* __restrict__ out) {
    const int tid = threadIdx.x;
    __shared__ double sred[256];
    double s = 0.0;
    for (int p = tid; p < NBLK; p += 256) s += partials[p];
    sred[tid] = s;
    __syncthreads();
    for (int off = 128; off > 0; off >>= 1) {
        if (tid < off) sred[tid] += sred[tid + off];
        __syncthreads();
    }
    if (tid == 0) out[0] = (float)(sred[0] / (double)(NIMG * H * W));
}

extern "C" void kernel_launch(void* const* d_in, const int* in_sizes, int n_in,
                              void* d_out, int out_size, void* d_ws, size_t ws_size,
                              hipStream_t stream) {
    const float* pred = (const float*)d_in[0];
    const int*   tgt  = (const int*)d_in[1];
    float* out = (float*)d_out;

    char* ws = (char*)d_ws;
    const size_t gbytes = (size_t)NIMG * NPIX * sizeof(float);   // 6,291,456 B
    float*  hpT      = (float*)(ws);
    float*  hnT      = (float*)(ws + gbytes);
    double* partials = (double*)(ws + 2 * gbytes);               // 6144 * 8 B
    int*    flags    = (int*)(ws + 2 * gbytes + (size_t)NBLK * sizeof(double));

    hipMemsetAsync(flags, 0, NIMG * sizeof(int), stream);
    edt_rows_kernel<<<NROWS / 4, 256, 0, stream>>>(tgt, hpT, hnT, flags);
    edt_cols_kernel<<<NBLK, 256, 0, stream>>>(hpT, hnT, pred, tgt, flags, partials);
    finalize_kernel<<<1, 256, 0, stream>>>(partials, out);
}

// Round 3
// 87.436 us; speedup vs baseline: 1.1909x; 1.1909x over previous
//
#include <hip/hip_runtime.h>
#include <math.h>

#define NIMG 24        // B*C = 8*3
#define H    256
#define W    256
#define NPIX (H * W)
#define NROWS (NIMG * H)
#define JPB  4                     // columns per pass-2 block (= waves/block)
#define NPART (NIMG * (W / JPB))   // 1536 pass-2 partials
#define BIGF 1.0e6f

// ---------------------------------------------------------------------------
// Wave-level inclusive max scans (64 lanes)
// ---------------------------------------------------------------------------
__device__ __forceinline__ float wscan_fwd_max(float v, int lane) {
#pragma unroll
    for (int off = 1; off < 64; off <<= 1) {
        float u = __shfl_up(v, off, 64);
        if (lane >= off) v = fmaxf(v, u);
    }
    return v;
}
__device__ __forceinline__ float wscan_rev_max(float v, int lane) {
#pragma unroll
    for (int off = 1; off < 64; off <<= 1) {
        float u = __shfl_down(v, off, 64);
        if (lane + off < 64) v = fmaxf(v, u);
    }
    return v;
}

// ---------------------------------------------------------------------------
// Pass 1: one WAVE per row (lane owns 4 cols). 1-D EDT both polarities via
// per-lane prefix + wave shfl-scan. Output: f = g_pos - g_neg (exactly one
// is nonzero per pixel, so one float encodes both; sign(f) = polarity).
// Row-major float4 stores -> fully coalesced, 6.3 MB.
// ---------------------------------------------------------------------------
__global__ void edt_rows_kernel(const int* __restrict__ tgt,
                                float* __restrict__ f,
                                int* __restrict__ flags) {
    const int tid  = blockIdx.x * 256 + threadIdx.x;
    const int gw   = tid >> 6;          // global wave id == row id
    const int lane = tid & 63;
    const int img  = gw >> 8;
    const int row  = gw & 255;

    const int4 tv = ((const int4*)(tgt + (img << 16) + (row << 8)))[lane];
    const float c0 = (float)(lane << 2);
    const float c1 = c0 + 1.0f, c2 = c0 + 2.0f, c3 = c0 + 3.0f;

    auto polarity = [&](bool z0, bool z1, bool z2, bool z3) -> float4 {
        // forward: last = inclusive cummax of (z ? col : -BIG)
        float a0 = z0 ? c0 : -BIGF;
        float a1 = fmaxf(z1 ? c1 : -BIGF, a0);
        float a2 = fmaxf(z2 ? c2 : -BIGF, a1);
        float a3 = fmaxf(z3 ? c3 : -BIGF, a2);
        float s  = wscan_fwd_max(a3, lane);
        float ex = __shfl_up(s, 1, 64);
        if (lane == 0) ex = -BIGF;
        // backward: inclusive reverse cummax of (z ? -col : -BIG); nxt = -that
        float b3 = z3 ? -c3 : -BIGF;
        float b2 = fmaxf(z2 ? -c2 : -BIGF, b3);
        float b1 = fmaxf(z1 ? -c1 : -BIGF, b2);
        float b0 = fmaxf(z0 ? -c0 : -BIGF, b1);
        float sr  = wscan_rev_max(b0, lane);
        float exr = __shfl_down(sr, 1, 64);
        if (lane == 63) exr = -BIGF;

        float l0 = fmaxf(ex, a0), l1 = fmaxf(ex, a1);
        float l2 = fmaxf(ex, a2), l3 = fmaxf(ex, a3);
        float n0 = fmaxf(exr, b0), n1 = fmaxf(exr, b1);
        float n2 = fmaxf(exr, b2), n3 = fmaxf(exr, b3);

        float4 g;
        g.x = fminf(fminf(c0 - l0, -n0 - c0), BIGF);
        g.y = fminf(fminf(c1 - l1, -n1 - c1), BIGF);
        g.z = fminf(fminf(c2 - l2, -n2 - c2), BIGF);
        g.w = fminf(fminf(c3 - l3, -n3 - c3), BIGF);
        return g;
    };

    const float4 gp = polarity(tv.x == 0, tv.y == 0, tv.z == 0, tv.w == 0);
    const float4 gn = polarity(tv.x != 0, tv.y != 0, tv.z != 0, tv.w != 0);
    float4 out;
    out.x = gp.x - gn.x;  out.y = gp.y - gn.y;
    out.z = gp.z - gn.z;  out.w = gp.w - gn.w;
    ((float4*)(f + (img << 16) + (row << 8)))[lane] = out;

    const int nz = tv.x | tv.y | tv.z | tv.w;
    if (__any(nz != 0)) {
        if (lane == 0) atomicOr(&flags[img], 1);
    }
}

// ---------------------------------------------------------------------------
// Pass 2: block = (img, group of 4 columns); wave w owns column j0+w, lane
// covers rows i = lane + 64q. Window-bounded exact min-plus:
//   D2[i] = min_{|k-i| <= g[i]} g_m[k]^2 + (i-k)^2   (g_m decoded from f)
// (minimizer must satisfy |i-k| <= g[i] since k=i gives g[i]^2). All finite
// terms are exact fp32 integers < 2^17 -> bitwise equal to full scan.
// ---------------------------------------------------------------------------
__global__ void edt_cols_kernel(const float* __restrict__ f,
                                const float* __restrict__ pred,
                                const int* __restrict__ flags,
                                double* __restrict__ partials) {
    const int blk  = blockIdx.x;           // img*64 + jg
    const int img  = blk >> 6;
    const int j0   = (blk & 63) << 2;
    const int t    = threadIdx.x;
    const int lane = t & 63;
    const int wid  = t >> 6;

    __shared__ float sf[JPB][264];
    __shared__ float sp[JPB][264];
    {
        const int base = (img << 16) + (t << 8) + j0;
        const float4 fv = *(const float4*)(f + base);
        const float4 pv = *(const float4*)(pred + base);
        sf[0][t] = fv.x; sf[1][t] = fv.y; sf[2][t] = fv.z; sf[3][t] = fv.w;
        sp[0][t] = pv.x; sp[1][t] = pv.y; sp[2][t] = pv.z; sp[3][t] = pv.w;
    }
    __syncthreads();

    const float* sc = sf[wid];             // wave-uniform column base
    const float* pc = sp[wid];
    const int iflag = flags[img];

    double acc = 0.0;
#pragma unroll
    for (int q = 0; q < 4; ++q) {
        const int i = lane + (q << 6);
        const float fv = sc[i];
        const bool  m  = fv > 0.0f;        // sign(f) = pixel polarity
        const float sgn = m ? 1.0f : -1.0f;
        const float gi = fabsf(fv);
        const int  gii = (int)gi;
        const int  lo  = (i - gii) > 0 ? (i - gii) : 0;
        const int  hi  = (i + gii) < (H - 1) ? (i + gii) : (H - 1);
        const float fi = (float)i;

        float dm = 3.0e38f;
        float dk = fi - (float)lo;
        for (int k = lo; k <= hi; ++k) {
            const float g = fmaxf(sgn * sc[k], 0.0f);   // g of needed polarity
            dm = fminf(dm, fmaf(g, g, dk * dk));
            dk -= 1.0f;
        }

        float d = m ? sqrtf(dm) : -sqrtf(dm);
        if (iflag == 0) d = 0.0f;
        const float p = pc[i];
        const float sig = 1.0f / (1.0f + expf(-p));
        acc += (double)sig * (double)d;
    }

    // wave reduce (double), then 4 wave sums -> partial
#pragma unroll
    for (int off = 32; off > 0; off >>= 1) acc += __shfl_down(acc, off, 64);
    __shared__ double wsum[4];
    if (lane == 0) wsum[wid] = acc;
    __syncthreads();
    if (t == 0) partials[blk] = (wsum[0] + wsum[1]) + (wsum[2] + wsum[3]);
}

// ---------------------------------------------------------------------------
// Finalize: deterministic sum of 1536 partials -> mean -> fp32
// ---------------------------------------------------------------------------
__global__ void finalize_kernel(const double* __restrict__ partials,
                                float* __restrict__ out) {
    const int tid = threadIdx.x;
    __shared__ double sred[256];
    double s = 0.0;
    for (int p = tid; p < NPART; p += 256) s += partials[p];
    sred[tid] = s;
    __syncthreads();
    for (int off = 128; off > 0; off >>= 1) {
        if (tid < off) sred[tid] += sred[tid + off];
        __syncthreads();
    }
    if (tid == 0) out[0] = (float)(sred[0] / (double)(NIMG * H * W));
}

extern "C" void kernel_launch(void* const* d_in, const int* in_sizes, int n_in,
                              void* d_out, int out_size, void* d_ws, size_t ws_size,
                              hipStream_t stream) {
    const float* pred = (const float*)d_in[0];
    const int*   tgt  = (const int*)d_in[1];
    float* out = (float*)d_out;

    char* ws = (char*)d_ws;
    const size_t fbytes = (size_t)NIMG * NPIX * sizeof(float);   // 6,291,456 B
    float*  fbuf     = (float*)(ws);
    double* partials = (double*)(ws + fbytes);                   // 1536 * 8 B
    int*    flags    = (int*)(ws + fbytes + (size_t)NPART * sizeof(double));

    hipMemsetAsync(flags, 0, NIMG * sizeof(int), stream);
    edt_rows_kernel<<<NROWS / 4, 256, 0, stream>>>(tgt, fbuf, flags);
    edt_cols_kernel<<<NIMG * (W / JPB), 256, 0, stream>>>(fbuf, pred, flags, partials);
    finalize_kernel<<<1, 256, 0, stream>>>(partials, out);
}

// Round 4
// 34.148 us; speedup vs baseline: 3.0494x; 2.5605x over previous
//
#include <hip/hip_runtime.h>
#include <math.h>

#define NIMG 24        // B*C = 8*3
#define H    256
#define W    256
#define NPIX (H * W)
#define NROWS (NIMG * H)
#define JPB  4                     // columns per pass-2 block (= waves/block)
#define NPART (NIMG * (W / JPB))   // 1536 pass-2 partials
#define BIGF 1.0e6f

// ---------------------------------------------------------------------------
// Wave-level inclusive max scans (64 lanes)
// ---------------------------------------------------------------------------
__device__ __forceinline__ float wscan_fwd_max(float v, int lane) {
#pragma unroll
    for (int off = 1; off < 64; off <<= 1) {
        float u = __shfl_up(v, off, 64);
        if (lane >= off) v = fmaxf(v, u);
    }
    return v;
}
__device__ __forceinline__ float wscan_rev_max(float v, int lane) {
#pragma unroll
    for (int off = 1; off < 64; off <<= 1) {
        float u = __shfl_down(v, off, 64);
        if (lane + off < 64) v = fmaxf(v, u);
    }
    return v;
}

// ---------------------------------------------------------------------------
// Pass 1: one WAVE per row (lane owns 4 cols). 1-D EDT both polarities via
// per-lane prefix + wave shfl-scan. Output: f = g_pos - g_neg (exactly one
// is nonzero per pixel, so one float encodes both; sign(f) = polarity).
// NO atomics (round-3 lesson: 6144 same-line device-scope atomicOrs
// serialized at ~23 ns each = the entire 58 us kernel duration).
// ---------------------------------------------------------------------------
__global__ void edt_rows_kernel(const int* __restrict__ tgt,
                                float* __restrict__ f) {
    const int tid  = blockIdx.x * 256 + threadIdx.x;
    const int gw   = tid >> 6;          // global wave id == row id
    const int lane = tid & 63;
    const int img  = gw >> 8;
    const int row  = gw & 255;

    const int4 tv = ((const int4*)(tgt + (img << 16) + (row << 8)))[lane];
    const float c0 = (float)(lane << 2);
    const float c1 = c0 + 1.0f, c2 = c0 + 2.0f, c3 = c0 + 3.0f;

    auto polarity = [&](bool z0, bool z1, bool z2, bool z3) -> float4 {
        // forward: last = inclusive cummax of (z ? col : -BIG)
        float a0 = z0 ? c0 : -BIGF;
        float a1 = fmaxf(z1 ? c1 : -BIGF, a0);
        float a2 = fmaxf(z2 ? c2 : -BIGF, a1);
        float a3 = fmaxf(z3 ? c3 : -BIGF, a2);
        float s  = wscan_fwd_max(a3, lane);
        float ex = __shfl_up(s, 1, 64);
        if (lane == 0) ex = -BIGF;
        // backward: inclusive reverse cummax of (z ? -col : -BIG); nxt = -that
        float b3 = z3 ? -c3 : -BIGF;
        float b2 = fmaxf(z2 ? -c2 : -BIGF, b3);
        float b1 = fmaxf(z1 ? -c1 : -BIGF, b2);
        float b0 = fmaxf(z0 ? -c0 : -BIGF, b1);
        float sr  = wscan_rev_max(b0, lane);
        float exr = __shfl_down(sr, 1, 64);
        if (lane == 63) exr = -BIGF;

        float l0 = fmaxf(ex, a0), l1 = fmaxf(ex, a1);
        float l2 = fmaxf(ex, a2), l3 = fmaxf(ex, a3);
        float n0 = fmaxf(exr, b0), n1 = fmaxf(exr, b1);
        float n2 = fmaxf(exr, b2), n3 = fmaxf(exr, b3);

        float4 g;
        g.x = fminf(fminf(c0 - l0, -n0 - c0), BIGF);
        g.y = fminf(fminf(c1 - l1, -n1 - c1), BIGF);
        g.z = fminf(fminf(c2 - l2, -n2 - c2), BIGF);
        g.w = fminf(fminf(c3 - l3, -n3 - c3), BIGF);
        return g;
    };

    const float4 gp = polarity(tv.x == 0, tv.y == 0, tv.z == 0, tv.w == 0);
    const float4 gn = polarity(tv.x != 0, tv.y != 0, tv.z != 0, tv.w != 0);
    float4 out;
    out.x = gp.x - gn.x;  out.y = gp.y - gn.y;
    out.z = gp.z - gn.z;  out.w = gp.w - gn.w;
    ((float4*)(f + (img << 16) + (row << 8)))[lane] = out;
}

// ---------------------------------------------------------------------------
// Pass 2: block = (img, group of 4 columns); wave w owns column j0+w, lane
// covers rows i = lane + 64q. Window-bounded exact min-plus:
//   D2[i] = min_{|k-i| <= g[i]} g_m[k]^2 + (i-k)^2   (g_m decoded from f)
// (minimizer must satisfy |i-k| <= g[i] since k=i gives g[i]^2). All finite
// terms are exact fp32 integers -> bitwise equal to full scan.
// Empty-mask flag, derived per column (no global flag needed):
//   mask empty <=> g_neg == BIG in every row <=> f == -BIG at every pixel
//   of this column. Nonempty mask => some row has g_neg < BIG => that row's
//   entry in EVERY column differs from -BIG.
// ---------------------------------------------------------------------------
__global__ void edt_cols_kernel(const float* __restrict__ f,
                                const float* __restrict__ pred,
                                double* __restrict__ partials) {
    const int blk  = blockIdx.x;           // img*64 + jg
    const int img  = blk >> 6;
    const int j0   = (blk & 63) << 2;
    const int t    = threadIdx.x;
    const int lane = t & 63;
    const int wid  = t >> 6;

    __shared__ float sf[JPB][264];
    __shared__ float sp[JPB][264];
    {
        const int base = (img << 16) + (t << 8) + j0;
        const float4 fv = *(const float4*)(f + base);
        const float4 pv = *(const float4*)(pred + base);
        sf[0][t] = fv.x; sf[1][t] = fv.y; sf[2][t] = fv.z; sf[3][t] = fv.w;
        sp[0][t] = pv.x; sp[1][t] = pv.y; sp[2][t] = pv.z; sp[3][t] = pv.w;
    }
    __syncthreads();

    const float* sc = sf[wid];             // wave-uniform column base
    const float* pc = sp[wid];

    float v0 = sc[lane], v1 = sc[lane + 64], v2 = sc[lane + 128], v3 = sc[lane + 192];
    const bool colempty =
        __all(v0 == -BIGF && v1 == -BIGF && v2 == -BIGF && v3 == -BIGF);

    double acc = 0.0;
    if (!colempty) {
        float vq[4] = {v0, v1, v2, v3};
#pragma unroll
        for (int q = 0; q < 4; ++q) {
            const int i = lane + (q << 6);
            const float fv = vq[q];
            const bool  m  = fv > 0.0f;        // sign(f) = pixel polarity
            const float sgn = m ? 1.0f : -1.0f;
            const float gi = fabsf(fv);
            const int  gii = (int)gi;
            const int  lo  = (i - gii) > 0 ? (i - gii) : 0;
            const int  hi  = (i + gii) < (H - 1) ? (i + gii) : (H - 1);
            const float fi = (float)i;

            float dm = 3.0e38f;
            float dk = fi - (float)lo;
            for (int k = lo; k <= hi; ++k) {
                const float g = fmaxf(sgn * sc[k], 0.0f);   // g of needed polarity
                dm = fminf(dm, fmaf(g, g, dk * dk));
                dk -= 1.0f;
            }

            const float d = m ? sqrtf(dm) : -sqrtf(dm);
            const float p = pc[i];
            const float sig = 1.0f / (1.0f + expf(-p));
            acc += (double)sig * (double)d;
        }
    }

    // wave reduce (double), then 4 wave sums -> partial
#pragma unroll
    for (int off = 32; off > 0; off >>= 1) acc += __shfl_down(acc, off, 64);
    __shared__ double wsum[4];
    if (lane == 0) wsum[wid] = acc;
    __syncthreads();
    if (t == 0) partials[blk] = (wsum[0] + wsum[1]) + (wsum[2] + wsum[3]);
}

// ---------------------------------------------------------------------------
// Finalize: deterministic sum of 1536 partials -> mean -> fp32
// ---------------------------------------------------------------------------
__global__ void finalize_kernel(const double* __restrict__ partials,
                                float* __restrict__ out) {
    const int tid = threadIdx.x;
    __shared__ double sred[256];
    double s = 0.0;
    for (int p = tid; p < NPART; p += 256) s += partials[p];
    sred[tid] = s;
    __syncthreads();
    for (int off = 128; off > 0; off >>= 1) {
        if (tid < off) sred[tid] += sred[tid + off];
        __syncthreads();
    }
    if (tid == 0) out[0] = (float)(sred[0] / (double)(NIMG * H * W));
}

extern "C" void kernel_launch(void* const* d_in, const int* in_sizes, int n_in,
                              void* d_out, int out_size, void* d_ws, size_t ws_size,
                              hipStream_t stream) {
    const float* pred = (const float*)d_in[0];
    const int*   tgt  = (const int*)d_in[1];
    float* out = (float*)d_out;

    char* ws = (char*)d_ws;
    const size_t fbytes = (size_t)NIMG * NPIX * sizeof(float);   // 6,291,456 B
    float*  fbuf     = (float*)(ws);
    double* partials = (double*)(ws + fbytes);                   // 1536 * 8 B

    edt_rows_kernel<<<NROWS / 4, 256, 0, stream>>>(tgt, fbuf);
    edt_cols_kernel<<<NIMG * (W / JPB), 256, 0, stream>>>(fbuf, pred, partials);
    finalize_kernel<<<1, 256, 0, stream>>>(partials, out);
}